// Round 1
// baseline (263.285 us; speedup 1.0000x reference)
//
#include <hip/hip_runtime.h>
#include <hip/hip_fp16.h>

// Idealizer: torsion angles + backbone frames -> atom14 coordinates.
// One thread per residue; each block computes ONE 256-residue tile of atoms
// 4..13 into LDS, then copies out coalesced (backbone straight from bb).
//
// Journal:
// R1: 176 VGPR reg-buffered -> 93 us. R2: forced 64 VGPR -> spill, 159 us.
// R4: scattered dword stores -> WRITE 266 MB (partial-line amplification).
// R5: LDS tile -> clean 82 MB writes, 2 blocks/CU, 63 us.
// R6: 4 blocks/CU, occupancy 32% -> 61 us (occupancy alone: flat).
// R7: -15% VALU but 3 blocks/CU (LDS 40960 + bounds(256,3)) -> 63 us (flat).
//     Model: dur ~ inst_work / issue_eff(occupancy); must improve BOTH.
//     Bank bug: lit stride 32 halves = 16 dwords -> 2 bank positions.
// R8: R7 insts + 4 blocks/CU (LDS 40716 <= 40960, no reg cap), lit stride
//     34 halves (full bank spread), single-tile blocks (grid 1954) -> 57 us.
// R9: THEORY: per-SIMD issue util only ~22%; occupancy-flat (R6) and
//     VALU-cut-sublinear (R7/R8) => latency-serialization bound. At 84 VGPR
//     the live set (~130 regs) can't fit -> compiler re-reads LDS per group
//     and serializes ds_read (~120cy) against uses. LDS caps us at 4 waves/
//     SIMD anyway, so 128 VGPRs are free: __launch_bounds__(256,4) + explicit
//     next-frame prefetch + early aa/LDS issue + unrolled copy-out for MLP.

struct F3 { float x, y, z; };

__device__ __forceinline__ F3 f3sub(F3 a, F3 b) { return {a.x-b.x, a.y-b.y, a.z-b.z}; }
__device__ __forceinline__ F3 f3cross(F3 a, F3 b) {
    return {a.y*b.z - a.z*b.y, a.z*b.x - a.x*b.z, a.x*b.y - a.y*b.x};
}
__device__ __forceinline__ float f3dot(F3 a, F3 b) { return a.x*b.x + a.y*b.y + a.z*b.z; }

// Dihedral sin/cos from two shared bond-crosses A=cross(u_k,u_k+1),
// B=cross(u_k+1,u_k+2) and the middle bond vector (signs cancel vs ref).
__device__ __forceinline__ void dihedral_from(F3 A, F3 B, F3 mid,
                                              float& s, float& c) {
    float x = f3dot(A, B);
    F3 w = f3cross(A, B);
    float y = f3dot(w, mid) * rsqrtf(fmaxf(f3dot(mid, mid), 1e-30f));
    float r2 = x * x + y * y;
    float rinv = rsqrtf(r2);
    bool ok = r2 > 1e-24f;
    s = ok ? y * rinv : 0.0f;   // atan2(0,0)=0 -> angle 0
    c = ok ? x * rinv : 1.0f;
}

#define DF_AA     100   // dwords/aa: 8 frames x 12 + 4 pad; 400B -> 16B-aligned
                        // rows, base bank (4*aai)%32 -> 8 positions
#define LIT_AA    34    // halves/aa: dword offset 17*aai+k -> full bank spread
#define OT_STRIDE 30    // output tile row: atoms 4..13

__global__ __launch_bounds__(256, 4) void idealizer_kernel(
    const int*   __restrict__ aa,       // (n,)
    const float* __restrict__ bb,       // (n,4,3)
    const float* __restrict__ tor,      // (n,4)
    const float* __restrict__ dframes,  // (21,8,4,4)
    const int*   __restrict__ gidx,     // (21,14)
    const float* __restrict__ amask,    // (21,14)
    const float* __restrict__ lit,      // (21,14,3)
    float*       __restrict__ out,      // (n,14,3)
    int n)
{
    __shared__ __align__(16) float  s_ot[256 * OT_STRIDE];  // 30720 B
    __shared__ __align__(16) float  s_df[21 * DF_AA];       //  8400 B
    __shared__ __align__(8)  __half s_lith[21 * LIT_AA];    //  1428 B
    __shared__ unsigned s_gpk[21];   // 10 x 3-bit group ids (atoms 4..13)
    __shared__ unsigned s_mbit[21];  // 10 x 1-bit atom mask (atoms 4..13)
    // total 40716 B -> 4 blocks/CU

    const int tid = threadIdx.x;
    // default_frames rows 0..2 (12 of 16 floats) per frame, fp32
    for (int j = tid; j < 21 * 8 * 12; j += 256) {
        int blk = j / 12, e = j - blk * 12;      // blk = aai*8+g
        s_df[(blk >> 3) * DF_AA + (blk & 7) * 12 + e] = dframes[blk * 16 + e];
    }
    for (int j = tid; j < 21 * 30; j += 256) {
        int a = j / 30, r = j - a * 30;
        s_lith[a * LIT_AA + r] = __float2half(lit[a * 42 + 12 + r]);
    }
    if (tid < 21) {
        unsigned gp = 0, mb = 0;
        #pragma unroll
        for (int a = 0; a < 10; a++) {
            gp |= ((unsigned)gidx[tid * 14 + 4 + a]) << (3 * a);
            mb |= (amask[tid * 14 + 4 + a] != 0.0f ? 1u : 0u) << a;
        }
        s_gpk[tid] = gp;
        s_mbit[tid] = mb;
    }
    __syncthreads();

    const int i0 = blockIdx.x * 256;
    const int i  = i0 + tid;
    if (i < n) {
        // ---- issue ALL global loads first (aa earliest: LDS reads hang off it)
        const int aai = aa[i];
        const float4* bb4 = (const float4*)bb;
        float4 q0 = bb4[i * 3 + 0];   // N.xyz, CA.x
        float4 q1 = bb4[i * 3 + 1];   // CA.yz, C.xy
        float Cz  = bb[i * 12 + 8];
        const int im = (i > 0)     ? i - 1 : 0;
        const int ip = (i < n - 1) ? i + 1 : 0;
        float4 t1 = bb4[im * 3 + 1];                 // C[i-1].xy in .z,.w
        float  t2 = bb[im * 12 + 8];                 // C[i-1].z
        float4 r0 = bb4[ip * 3 + 0];                 // N[i+1], CA[i+1].x
        float2 r1 = ((const float2*)bb)[ip * 6 + 2]; // CA[i+1].yz
        float4 tv = ((const float4*)tor)[i];

        // ---- aa-dependent LDS reads: issue early, overlap with dihedrals ----
        const unsigned gpk  = s_gpk[aai];
        const unsigned mbit = s_mbit[aai];
        float la[30];
        {
            const __half2* lh = (const __half2*)&s_lith[aai * LIT_AA];
            #pragma unroll
            for (int k = 0; k < 15; k++) {
                float2 t = __half22float2(lh[k]);
                la[2*k] = t.x; la[2*k+1] = t.y;
            }
        }
        // prefetch frame g=0 rows (group loop prefetches g+1 each step)
        const float* dfa = &s_df[aai * DF_AA];
        float4 nd0, nd1, nd2;
        {
            const float4* dfr = (const float4*)dfa;
            nd0 = dfr[0]; nd1 = dfr[1]; nd2 = dfr[2];
        }

        F3 Np  = {q0.x, q0.y, q0.z};
        F3 CAp = {q0.w, q1.x, q1.y};
        F3 Cp  = {q1.z, q1.w, Cz};
        F3 Cm  = {t1.z, t1.w, t2};
        F3 Nn  = {r0.x, r0.y, r0.z};
        F3 CAn = {r0.w, r1.x, r1.y};

        // ---- backbone dihedrals via shared bond crosses ----
        F3 u1 = f3sub(Np, Cm);
        F3 u2 = f3sub(CAp, Np);
        F3 u3 = f3sub(Cp, CAp);
        F3 u4 = f3sub(Nn, Cp);
        F3 u5 = f3sub(CAn, Nn);
        F3 c12 = f3cross(u1, u2), c23 = f3cross(u2, u3);
        F3 c34 = f3cross(u3, u4), c45 = f3cross(u4, u5);
        float s_ph, c_ph, s_ps, c_ps, s_om, c_om;
        dihedral_from(c12, c23, u2, s_ph, c_ph);   // phi
        dihedral_from(c23, c34, u3, s_ps, c_ps);   // psi
        dihedral_from(c34, c45, u4, s_om, c_om);   // omega
        if (i == 0)     { s_ph = 0.0f; c_ph = 1.0f; }
        if (i == n - 1) { s_ps = 0.0f; c_ps = 1.0f; s_om = 0.0f; c_om = 1.0f; }

        // ---- backbone frame from reference (N, CA, C) ----
        const float eps = 1e-20f;
        F3 nv = f3sub(Np, CAp);
        F3 cv = f3sub(Cp, CAp);
        float cx = cv.x, cy = cv.y, cz2 = cv.z;
        float d2xy  = cx * cx + cy * cy;
        float inrm  = rsqrtf(eps + d2xy);
        float s1 = -cy * inrm, c1 = cx * inrm;
        float inrm2 = rsqrtf(eps + d2xy + cz2 * cz2);
        float s2v = cz2 * inrm2, c2v = sqrtf(d2xy) * inrm2;
        float Rc00 = c2v * c1,  Rc01 = -c2v * s1, Rc02 = s2v;
        float Rc10 = s1,        Rc11 = c1,        Rc12 = 0.0f;
        float Rc20 = -s2v * c1, Rc21 = s2v * s1,  Rc22 = c2v;
        float n2y = Rc10 * nv.x + Rc11 * nv.y + Rc12 * nv.z;
        float n2z = Rc20 * nv.x + Rc21 * nv.y + Rc22 * nv.z;
        float inrm3 = rsqrtf(eps + n2y * n2y + n2z * n2z);
        float sn = -n2z * inrm3, cn = n2y * inrm3;
        float M10 = cn * Rc10 - sn * Rc20, M11 = cn * Rc11 - sn * Rc21, M12 = cn * Rc12 - sn * Rc22;
        float M20 = sn * Rc10 + cn * Rc20, M21 = sn * Rc11 + cn * Rc21;
        float M22 = sn * Rc12 + cn * Rc22;
        // bb_r = (Rn @ Rc)^T
        float B00 = Rc00, B01 = M10, B02 = M20;
        float B10 = Rc01, B11 = M11, B12 = M21;
        float B20 = Rc02, B21 = M12, B22 = M22;

        // ---- per-frame sin/cos: [identity, omega, phi, psi, tor0..3] ----
        float sang[8], cang[8];
        sang[0] = 0.0f; cang[0] = 1.0f;
        sang[1] = s_om; cang[1] = c_om;
        sang[2] = s_ph; cang[2] = c_ph;
        sang[3] = s_ps; cang[3] = c_ps;
        __sincosf(tv.x, &sang[4], &cang[4]);
        __sincosf(tv.y, &sang[5], &cang[5]);
        __sincosf(tv.z, &sang[6], &cang[6]);
        __sincosf(tv.w, &sang[7], &cang[7]);

        float v[30];
        #pragma unroll
        for (int k = 0; k < 30; k++) v[k] = 0.0f;

        // ---- group chain in LOCAL (backbone-relative) coords ----
        // Software-pipelined: frame g+1's LDS rows are fetched before the
        // 130-op atom-select of frame g, hiding the ~120cy ds_read latency.
        float L00, L01, L02, L10, L11, L12, L20, L21, L22, Lx, Ly, Lz;
        #pragma unroll
        for (int g = 0; g < 8; g++) {
            float4 d0 = nd0, d1 = nd1, d2 = nd2;  // rows (m,m,m,t)
            if (g < 7) {
                const float4* dfr = (const float4*)(dfa + (g + 1) * 12);
                nd0 = dfr[0]; nd1 = dfr[1]; nd2 = dfr[2];
            }
            float sA = sang[g], cA = cang[g];
            // fr = dr @ Ra(angle)
            float f00 = d0.x, f01 = cA * d0.y + sA * d0.z, f02 = cA * d0.z - sA * d0.y;
            float f10 = d1.x, f11 = cA * d1.y + sA * d1.z, f12 = cA * d1.z - sA * d1.y;
            float f20 = d2.x, f21 = cA * d2.y + sA * d2.z, f22 = cA * d2.z - sA * d2.y;
            if (g <= 4) {
                L00 = f00; L01 = f01; L02 = f02;
                L10 = f10; L11 = f11; L12 = f12;
                L20 = f20; L21 = f21; L22 = f22;
                Lx = d0.w; Ly = d1.w; Lz = d2.w;
            } else {
                float n00 = L00 * f00 + L01 * f10 + L02 * f20;
                float n01 = L00 * f01 + L01 * f11 + L02 * f21;
                float n02 = L00 * f02 + L01 * f12 + L02 * f22;
                float n10 = L10 * f00 + L11 * f10 + L12 * f20;
                float n11 = L10 * f01 + L11 * f11 + L12 * f21;
                float n12 = L10 * f02 + L11 * f12 + L12 * f22;
                float n20 = L20 * f00 + L21 * f10 + L22 * f20;
                float n21 = L20 * f01 + L21 * f11 + L22 * f21;
                float n22 = L20 * f02 + L21 * f12 + L22 * f22;
                float ntx = L00 * d0.w + L01 * d1.w + L02 * d2.w + Lx;
                float nty = L10 * d0.w + L11 * d1.w + L12 * d2.w + Ly;
                float ntz = L20 * d0.w + L21 * d1.w + L22 * d2.w + Lz;
                L00 = n00; L01 = n01; L02 = n02;
                L10 = n10; L11 = n11; L12 = n12;
                L20 = n20; L21 = n21; L22 = n22;
                Lx = ntx; Ly = nty; Lz = ntz;
            }

            // dense branchless select: local q for atoms whose group == g
            #pragma unroll
            for (int a = 0; a < 10; a++) {
                bool sel = ((gpk >> (3 * a)) & 7u) == (unsigned)g;
                float qx = fmaf(L00, la[3*a], fmaf(L01, la[3*a+1], fmaf(L02, la[3*a+2], Lx)));
                float qy = fmaf(L10, la[3*a], fmaf(L11, la[3*a+1], fmaf(L12, la[3*a+2], Ly)));
                float qz = fmaf(L20, la[3*a], fmaf(L21, la[3*a+1], fmaf(L22, la[3*a+2], Lz)));
                v[3*a]   = sel ? qx : v[3*a];
                v[3*a+1] = sel ? qy : v[3*a+1];
                v[3*a+2] = sel ? qz : v[3*a+2];
            }
        }

        // ---- apply backbone frame + mask ONCE per atom ----
        #pragma unroll
        for (int a = 0; a < 10; a++) {
            float mk = ((mbit >> a) & 1u) ? 1.0f : 0.0f;
            float qx = v[3*a], qy = v[3*a+1], qz = v[3*a+2];
            v[3*a]   = mk * fmaf(B00, qx, fmaf(B01, qy, fmaf(B02, qz, CAp.x)));
            v[3*a+1] = mk * fmaf(B10, qx, fmaf(B11, qy, fmaf(B12, qz, CAp.y)));
            v[3*a+2] = mk * fmaf(B20, qx, fmaf(B21, qy, fmaf(B22, qz, CAp.z)));
        }

        // ---- tile row write: 15 x ds_write_b64 ----
        float2* so2 = (float2*)&s_ot[tid * OT_STRIDE];
        #pragma unroll
        for (int k = 0; k < 15; k++)
            so2[k] = make_float2(v[2*k], v[2*k+1]);
    }

    __syncthreads();

    // ---- coalesced copy-out, division-free ----
    int m = n - i0; if (m > 256) m = 256;
    float2* gout = (float2*)(out + (size_t)i0 * 42);
    const float2* bbt = (const float2*)(bb + (size_t)i0 * 12);
    if (m == 256) {
        // full tile: compile-time trip count 21 -> all LDS reads + stores
        // can be batched by the scheduler (MLP) instead of loop-carried.
        int r = (tid * 24967) >> 19;   // tid/21 (magic, exact for 0..255)
        int j = tid - r * 21;
        #pragma unroll
        for (int k = 0; k < 21; k++) {
            int off = tid + (k << 8);
            int bi = (j < 6) ? (r * 6 + j) : 0;        // clamped-safe index
            float2 gval = bbt[bi];
            int tj = (j < 6) ? 0 : (j - 6);
            const float* tp = &s_ot[r * OT_STRIDE + 2 * tj];
            float2 lval = make_float2(tp[0], tp[1]);
            gout[off] = (j < 6) ? gval : lval;
            r += 12; j += 4;                           // 256 = 12*21 + 4
            if (j >= 21) { j -= 21; r += 1; }
        }
    } else {
        const int cnt2 = m * 21;
        int r = tid / 21;
        int j = tid - r * 21;
        for (int off = tid; off < cnt2; off += 256) {
            int bi = (j < 6) ? (r * 6 + j) : 0;
            float2 gval = bbt[bi];
            int tj = (j < 6) ? 0 : (j - 6);
            const float* tp = &s_ot[r * OT_STRIDE + 2 * tj];
            float2 lval = make_float2(tp[0], tp[1]);
            gout[off] = (j < 6) ? gval : lval;
            r += 12; j += 4;
            if (j >= 21) { j -= 21; r += 1; }
        }
    }
}

extern "C" void kernel_launch(void* const* d_in, const int* in_sizes, int n_in,
                              void* d_out, int out_size, void* d_ws, size_t ws_size,
                              hipStream_t stream) {
    const int*   aa  = (const int*)d_in[0];
    const float* bb  = (const float*)d_in[1];
    const float* tor = (const float*)d_in[2];
    const float* df  = (const float*)d_in[3];
    const int*   gi  = (const int*)d_in[4];
    const float* am  = (const float*)d_in[5];
    const float* lp  = (const float*)d_in[6];
    float* outp = (float*)d_out;
    const int n = in_sizes[0];
    const int blocks = (n + 255) / 256;   // one 256-residue tile per block
    idealizer_kernel<<<blocks, 256, 0, stream>>>(aa, bb, tor, df, gi, am, lp, outp, n);
}

// Round 2
// 141.269 us; speedup vs baseline: 1.8637x; 1.8637x over previous
//
#include <hip/hip_runtime.h>
#include <hip/hip_fp16.h>

// Idealizer: torsion angles + backbone frames -> atom14 coordinates.
// One thread per residue; each block computes ONE 256-residue tile of atoms
// 4..13 into LDS, then copies out coalesced (backbone straight from bb).
//
// Journal:
// R1: 176 VGPR reg-buffered -> 93 us. R2: forced 64 VGPR -> spill, 159 us.
// R4: scattered dword stores -> WRITE 266 MB (partial-line amplification).
// R5: LDS tile -> clean 82 MB writes, 2 blocks/CU, 63 us.
// R6: 4 blocks/CU, occupancy 32% -> 61 us (occupancy alone: flat).
// R7: -15% VALU but 3 blocks/CU (LDS 40960 + bounds(256,3)) -> 63 us (flat).
//     Model: dur ~ inst_work / issue_eff(occupancy); must improve BOTH.
// R8: R7 insts + 4 blocks/CU (LDS 40716, no reg cap), lit stride 34 halves,
//     single-tile blocks (grid 1954) -> 57 us. VGPR 84 (compiler default).
// R9: FAILED 171us. __launch_bounds__(256,4) did NOT mean "4 waves/EU, cap
//     128" on this toolchain: compiler emitted 64 VGPR -> massive scratch
//     spill (FETCH 20->133MB, WRITE 82->258MB, VALUBusy 47->17%). Same
//     failure mode as R2. launch_bounds arg2 is unusable here.
// R10: one-variable fix of R9: __launch_bounds__(256) +
//     __attribute__((amdgpu_waves_per_eu(2,4))): min 2 (cap 256, can't
//     spill), max 4 (LDS caps at 4 waves/SIMD anyway -> allocator free to
//     use up to 128+ regs). Keeps R9 scheduling content (early global/LDS
//     issue, frame g+1 prefetch, unrolled full-tile copy-out) so its effect
//     is finally measured unconfounded. Predict VGPR ~110-150, FETCH ~20MB,
//     WRITE 82MB, dur 45-57us.

struct F3 { float x, y, z; };

__device__ __forceinline__ F3 f3sub(F3 a, F3 b) { return {a.x-b.x, a.y-b.y, a.z-b.z}; }
__device__ __forceinline__ F3 f3cross(F3 a, F3 b) {
    return {a.y*b.z - a.z*b.y, a.z*b.x - a.x*b.z, a.x*b.y - a.y*b.x};
}
__device__ __forceinline__ float f3dot(F3 a, F3 b) { return a.x*b.x + a.y*b.y + a.z*b.z; }

// Dihedral sin/cos from two shared bond-crosses A=cross(u_k,u_k+1),
// B=cross(u_k+1,u_k+2) and the middle bond vector (signs cancel vs ref).
__device__ __forceinline__ void dihedral_from(F3 A, F3 B, F3 mid,
                                              float& s, float& c) {
    float x = f3dot(A, B);
    F3 w = f3cross(A, B);
    float y = f3dot(w, mid) * rsqrtf(fmaxf(f3dot(mid, mid), 1e-30f));
    float r2 = x * x + y * y;
    float rinv = rsqrtf(r2);
    bool ok = r2 > 1e-24f;
    s = ok ? y * rinv : 0.0f;   // atan2(0,0)=0 -> angle 0
    c = ok ? x * rinv : 1.0f;
}

#define DF_AA     100   // dwords/aa: 8 frames x 12 + 4 pad; 400B -> 16B-aligned
                        // rows, base bank (4*aai)%32 -> 8 positions
#define LIT_AA    34    // halves/aa: dword offset 17*aai+k -> full bank spread
#define OT_STRIDE 30    // output tile row: atoms 4..13

__global__ __launch_bounds__(256)
__attribute__((amdgpu_waves_per_eu(2, 4)))
void idealizer_kernel(
    const int*   __restrict__ aa,       // (n,)
    const float* __restrict__ bb,       // (n,4,3)
    const float* __restrict__ tor,      // (n,4)
    const float* __restrict__ dframes,  // (21,8,4,4)
    const int*   __restrict__ gidx,     // (21,14)
    const float* __restrict__ amask,    // (21,14)
    const float* __restrict__ lit,      // (21,14,3)
    float*       __restrict__ out,      // (n,14,3)
    int n)
{
    __shared__ __align__(16) float  s_ot[256 * OT_STRIDE];  // 30720 B
    __shared__ __align__(16) float  s_df[21 * DF_AA];       //  8400 B
    __shared__ __align__(8)  __half s_lith[21 * LIT_AA];    //  1428 B
    __shared__ unsigned s_gpk[21];   // 10 x 3-bit group ids (atoms 4..13)
    __shared__ unsigned s_mbit[21];  // 10 x 1-bit atom mask (atoms 4..13)
    // total 40716 B -> 4 blocks/CU

    const int tid = threadIdx.x;
    // default_frames rows 0..2 (12 of 16 floats) per frame, fp32
    for (int j = tid; j < 21 * 8 * 12; j += 256) {
        int blk = j / 12, e = j - blk * 12;      // blk = aai*8+g
        s_df[(blk >> 3) * DF_AA + (blk & 7) * 12 + e] = dframes[blk * 16 + e];
    }
    for (int j = tid; j < 21 * 30; j += 256) {
        int a = j / 30, r = j - a * 30;
        s_lith[a * LIT_AA + r] = __float2half(lit[a * 42 + 12 + r]);
    }
    if (tid < 21) {
        unsigned gp = 0, mb = 0;
        #pragma unroll
        for (int a = 0; a < 10; a++) {
            gp |= ((unsigned)gidx[tid * 14 + 4 + a]) << (3 * a);
            mb |= (amask[tid * 14 + 4 + a] != 0.0f ? 1u : 0u) << a;
        }
        s_gpk[tid] = gp;
        s_mbit[tid] = mb;
    }
    __syncthreads();

    const int i0 = blockIdx.x * 256;
    const int i  = i0 + tid;
    if (i < n) {
        // ---- issue ALL global loads first (aa earliest: LDS reads hang off it)
        const int aai = aa[i];
        const float4* bb4 = (const float4*)bb;
        float4 q0 = bb4[i * 3 + 0];   // N.xyz, CA.x
        float4 q1 = bb4[i * 3 + 1];   // CA.yz, C.xy
        float Cz  = bb[i * 12 + 8];
        const int im = (i > 0)     ? i - 1 : 0;
        const int ip = (i < n - 1) ? i + 1 : 0;
        float4 t1 = bb4[im * 3 + 1];                 // C[i-1].xy in .z,.w
        float  t2 = bb[im * 12 + 8];                 // C[i-1].z
        float4 r0 = bb4[ip * 3 + 0];                 // N[i+1], CA[i+1].x
        float2 r1 = ((const float2*)bb)[ip * 6 + 2]; // CA[i+1].yz
        float4 tv = ((const float4*)tor)[i];

        // ---- aa-dependent LDS reads: issue early, overlap with dihedrals ----
        const unsigned gpk  = s_gpk[aai];
        const unsigned mbit = s_mbit[aai];
        float la[30];
        {
            const __half2* lh = (const __half2*)&s_lith[aai * LIT_AA];
            #pragma unroll
            for (int k = 0; k < 15; k++) {
                float2 t = __half22float2(lh[k]);
                la[2*k] = t.x; la[2*k+1] = t.y;
            }
        }
        // prefetch frame g=0 rows (group loop prefetches g+1 each step)
        const float* dfa = &s_df[aai * DF_AA];
        float4 nd0, nd1, nd2;
        {
            const float4* dfr = (const float4*)dfa;
            nd0 = dfr[0]; nd1 = dfr[1]; nd2 = dfr[2];
        }

        F3 Np  = {q0.x, q0.y, q0.z};
        F3 CAp = {q0.w, q1.x, q1.y};
        F3 Cp  = {q1.z, q1.w, Cz};
        F3 Cm  = {t1.z, t1.w, t2};
        F3 Nn  = {r0.x, r0.y, r0.z};
        F3 CAn = {r0.w, r1.x, r1.y};

        // ---- backbone dihedrals via shared bond crosses ----
        F3 u1 = f3sub(Np, Cm);
        F3 u2 = f3sub(CAp, Np);
        F3 u3 = f3sub(Cp, CAp);
        F3 u4 = f3sub(Nn, Cp);
        F3 u5 = f3sub(CAn, Nn);
        F3 c12 = f3cross(u1, u2), c23 = f3cross(u2, u3);
        F3 c34 = f3cross(u3, u4), c45 = f3cross(u4, u5);
        float s_ph, c_ph, s_ps, c_ps, s_om, c_om;
        dihedral_from(c12, c23, u2, s_ph, c_ph);   // phi
        dihedral_from(c23, c34, u3, s_ps, c_ps);   // psi
        dihedral_from(c34, c45, u4, s_om, c_om);   // omega
        if (i == 0)     { s_ph = 0.0f; c_ph = 1.0f; }
        if (i == n - 1) { s_ps = 0.0f; c_ps = 1.0f; s_om = 0.0f; c_om = 1.0f; }

        // ---- backbone frame from reference (N, CA, C) ----
        const float eps = 1e-20f;
        F3 nv = f3sub(Np, CAp);
        F3 cv = f3sub(Cp, CAp);
        float cx = cv.x, cy = cv.y, cz2 = cv.z;
        float d2xy  = cx * cx + cy * cy;
        float inrm  = rsqrtf(eps + d2xy);
        float s1 = -cy * inrm, c1 = cx * inrm;
        float inrm2 = rsqrtf(eps + d2xy + cz2 * cz2);
        float s2v = cz2 * inrm2, c2v = sqrtf(d2xy) * inrm2;
        float Rc00 = c2v * c1,  Rc01 = -c2v * s1, Rc02 = s2v;
        float Rc10 = s1,        Rc11 = c1,        Rc12 = 0.0f;
        float Rc20 = -s2v * c1, Rc21 = s2v * s1,  Rc22 = c2v;
        float n2y = Rc10 * nv.x + Rc11 * nv.y + Rc12 * nv.z;
        float n2z = Rc20 * nv.x + Rc21 * nv.y + Rc22 * nv.z;
        float inrm3 = rsqrtf(eps + n2y * n2y + n2z * n2z);
        float sn = -n2z * inrm3, cn = n2y * inrm3;
        float M10 = cn * Rc10 - sn * Rc20, M11 = cn * Rc11 - sn * Rc21, M12 = cn * Rc12 - sn * Rc22;
        float M20 = sn * Rc10 + cn * Rc20, M21 = sn * Rc11 + cn * Rc21;
        float M22 = sn * Rc12 + cn * Rc22;
        // bb_r = (Rn @ Rc)^T
        float B00 = Rc00, B01 = M10, B02 = M20;
        float B10 = Rc01, B11 = M11, B12 = M21;
        float B20 = Rc02, B21 = M12, B22 = M22;

        // ---- per-frame sin/cos: [identity, omega, phi, psi, tor0..3] ----
        float sang[8], cang[8];
        sang[0] = 0.0f; cang[0] = 1.0f;
        sang[1] = s_om; cang[1] = c_om;
        sang[2] = s_ph; cang[2] = c_ph;
        sang[3] = s_ps; cang[3] = c_ps;
        __sincosf(tv.x, &sang[4], &cang[4]);
        __sincosf(tv.y, &sang[5], &cang[5]);
        __sincosf(tv.z, &sang[6], &cang[6]);
        __sincosf(tv.w, &sang[7], &cang[7]);

        float v[30];
        #pragma unroll
        for (int k = 0; k < 30; k++) v[k] = 0.0f;

        // ---- group chain in LOCAL (backbone-relative) coords ----
        // Software-pipelined: frame g+1's LDS rows are fetched before the
        // 130-op atom-select of frame g, hiding the ~120cy ds_read latency.
        float L00, L01, L02, L10, L11, L12, L20, L21, L22, Lx, Ly, Lz;
        #pragma unroll
        for (int g = 0; g < 8; g++) {
            float4 d0 = nd0, d1 = nd1, d2 = nd2;  // rows (m,m,m,t)
            if (g < 7) {
                const float4* dfr = (const float4*)(dfa + (g + 1) * 12);
                nd0 = dfr[0]; nd1 = dfr[1]; nd2 = dfr[2];
            }
            float sA = sang[g], cA = cang[g];
            // fr = dr @ Ra(angle)
            float f00 = d0.x, f01 = cA * d0.y + sA * d0.z, f02 = cA * d0.z - sA * d0.y;
            float f10 = d1.x, f11 = cA * d1.y + sA * d1.z, f12 = cA * d1.z - sA * d1.y;
            float f20 = d2.x, f21 = cA * d2.y + sA * d2.z, f22 = cA * d2.z - sA * d2.y;
            if (g <= 4) {
                L00 = f00; L01 = f01; L02 = f02;
                L10 = f10; L11 = f11; L12 = f12;
                L20 = f20; L21 = f21; L22 = f22;
                Lx = d0.w; Ly = d1.w; Lz = d2.w;
            } else {
                float n00 = L00 * f00 + L01 * f10 + L02 * f20;
                float n01 = L00 * f01 + L01 * f11 + L02 * f21;
                float n02 = L00 * f02 + L01 * f12 + L02 * f22;
                float n10 = L10 * f00 + L11 * f10 + L12 * f20;
                float n11 = L10 * f01 + L11 * f11 + L12 * f21;
                float n12 = L10 * f02 + L11 * f12 + L12 * f22;
                float n20 = L20 * f00 + L21 * f10 + L22 * f20;
                float n21 = L20 * f01 + L21 * f11 + L22 * f21;
                float n22 = L20 * f02 + L21 * f12 + L22 * f22;
                float ntx = L00 * d0.w + L01 * d1.w + L02 * d2.w + Lx;
                float nty = L10 * d0.w + L11 * d1.w + L12 * d2.w + Ly;
                float ntz = L20 * d0.w + L21 * d1.w + L22 * d2.w + Lz;
                L00 = n00; L01 = n01; L02 = n02;
                L10 = n10; L11 = n11; L12 = n12;
                L20 = n20; L21 = n21; L22 = n22;
                Lx = ntx; Ly = nty; Lz = ntz;
            }

            // dense branchless select: local q for atoms whose group == g
            #pragma unroll
            for (int a = 0; a < 10; a++) {
                bool sel = ((gpk >> (3 * a)) & 7u) == (unsigned)g;
                float qx = fmaf(L00, la[3*a], fmaf(L01, la[3*a+1], fmaf(L02, la[3*a+2], Lx)));
                float qy = fmaf(L10, la[3*a], fmaf(L11, la[3*a+1], fmaf(L12, la[3*a+2], Ly)));
                float qz = fmaf(L20, la[3*a], fmaf(L21, la[3*a+1], fmaf(L22, la[3*a+2], Lz)));
                v[3*a]   = sel ? qx : v[3*a];
                v[3*a+1] = sel ? qy : v[3*a+1];
                v[3*a+2] = sel ? qz : v[3*a+2];
            }
        }

        // ---- apply backbone frame + mask ONCE per atom ----
        #pragma unroll
        for (int a = 0; a < 10; a++) {
            float mk = ((mbit >> a) & 1u) ? 1.0f : 0.0f;
            float qx = v[3*a], qy = v[3*a+1], qz = v[3*a+2];
            v[3*a]   = mk * fmaf(B00, qx, fmaf(B01, qy, fmaf(B02, qz, CAp.x)));
            v[3*a+1] = mk * fmaf(B10, qx, fmaf(B11, qy, fmaf(B12, qz, CAp.y)));
            v[3*a+2] = mk * fmaf(B20, qx, fmaf(B21, qy, fmaf(B22, qz, CAp.z)));
        }

        // ---- tile row write: 15 x ds_write_b64 ----
        float2* so2 = (float2*)&s_ot[tid * OT_STRIDE];
        #pragma unroll
        for (int k = 0; k < 15; k++)
            so2[k] = make_float2(v[2*k], v[2*k+1]);
    }

    __syncthreads();

    // ---- coalesced copy-out, division-free ----
    int m = n - i0; if (m > 256) m = 256;
    float2* gout = (float2*)(out + (size_t)i0 * 42);
    const float2* bbt = (const float2*)(bb + (size_t)i0 * 12);
    if (m == 256) {
        // full tile: compile-time trip count 21 -> all LDS reads + stores
        // can be batched by the scheduler (MLP) instead of loop-carried.
        int r = (tid * 24967) >> 19;   // tid/21 (magic, exact for 0..255)
        int j = tid - r * 21;
        #pragma unroll
        for (int k = 0; k < 21; k++) {
            int off = tid + (k << 8);
            int bi = (j < 6) ? (r * 6 + j) : 0;        // clamped-safe index
            float2 gval = bbt[bi];
            int tj = (j < 6) ? 0 : (j - 6);
            const float* tp = &s_ot[r * OT_STRIDE + 2 * tj];
            float2 lval = make_float2(tp[0], tp[1]);
            gout[off] = (j < 6) ? gval : lval;
            r += 12; j += 4;                           // 256 = 12*21 + 4
            if (j >= 21) { j -= 21; r += 1; }
        }
    } else {
        const int cnt2 = m * 21;
        int r = tid / 21;
        int j = tid - r * 21;
        for (int off = tid; off < cnt2; off += 256) {
            int bi = (j < 6) ? (r * 6 + j) : 0;
            float2 gval = bbt[bi];
            int tj = (j < 6) ? 0 : (j - 6);
            const float* tp = &s_ot[r * OT_STRIDE + 2 * tj];
            float2 lval = make_float2(tp[0], tp[1]);
            gout[off] = (j < 6) ? gval : lval;
            r += 12; j += 4;
            if (j >= 21) { j -= 21; r += 1; }
        }
    }
}

extern "C" void kernel_launch(void* const* d_in, const int* in_sizes, int n_in,
                              void* d_out, int out_size, void* d_ws, size_t ws_size,
                              hipStream_t stream) {
    const int*   aa  = (const int*)d_in[0];
    const float* bb  = (const float*)d_in[1];
    const float* tor = (const float*)d_in[2];
    const float* df  = (const float*)d_in[3];
    const int*   gi  = (const int*)d_in[4];
    const float* am  = (const float*)d_in[5];
    const float* lp  = (const float*)d_in[6];
    float* outp = (float*)d_out;
    const int n = in_sizes[0];
    const int blocks = (n + 255) / 256;   // one 256-residue tile per block
    idealizer_kernel<<<blocks, 256, 0, stream>>>(aa, bb, tor, df, gi, am, lp, outp, n);
}

// Round 5
// 137.269 us; speedup vs baseline: 1.9180x; 1.0291x over previous
//
#include <hip/hip_runtime.h>
#include <hip/hip_fp16.h>

// Idealizer: torsion angles + backbone frames -> atom14 coordinates.
// One thread per residue; each block computes ONE 256-residue tile of atoms
// 4..13 into LDS, then copies out coalesced (backbone straight from bb).
//
// Journal:
// R1: 176 VGPR reg-buffered -> 93 us. R2: forced 64 VGPR -> spill, 159 us.
// R4: scattered dword stores -> WRITE 266 MB (partial-line amplification).
// R5: LDS tile -> clean 82 MB writes, 2 blocks/CU, 63 us.
// R6: 4 blocks/CU, occupancy 32% -> 61 us (occupancy alone: flat).
// R7: -15% VALU but 3 blocks/CU -> 63 us (flat). Model: need inst-work AND
//     issue-eff together.
// R8: 4 blocks/CU + full bank spread -> 57 us. VGPR 84 (compiler default).
// R9: FAILED 171us. __launch_bounds__(256,4) => compiler emitted 64 VGPR ->
//     scratch spill (FETCH 133MB, WRITE 258MB, VALUBusy 17%). arg2 unusable.
// R10: WIN ~47us (fill kernels now top rocprof sort). waves_per_eu(2,4)
//     unlocked regs; R9 scheduling content (early issue, frame prefetch,
//     unrolled copyout) delivered. Register-starvation theory confirmed.
// R11: dense select loop (8 groups x 10 atoms x 14 ops = 1120) is 75% of
//     VALU. Replace with per-(aa,atom) staged constants A,U,V where
//     q_local = A + c*U + s*V  (dr@(Ra@lit)+dt refactored). Per atom: 3
//     ds_read_b64 + 6 cvt + 6 fma + sc read + 3 conditional chain applies
//     (fr6/fr5/fr4 if g>=7/6/5) + backbone. U,V fp16, A fp32, sc fp32 in
//     per-thread row slot. VALU ~1780 -> ~1160. Predict 33-38 us.
// R12: never ran — broker infra failure ("container failed twice").
// R13: R12 FAILED COMPILE: local float M12 shadowed struct M12 at the
//     F4/F5/F6 declarations. Lesson: ALWAYS compile-check resubmits.
//     Fix: rename struct M12 -> Xf12 (type name only, zero semantics).

struct F3 { float x, y, z; };

__device__ __forceinline__ F3 f3sub(F3 a, F3 b) { return {a.x-b.x, a.y-b.y, a.z-b.z}; }
__device__ __forceinline__ F3 f3cross(F3 a, F3 b) {
    return {a.y*b.z - a.z*b.y, a.z*b.x - a.x*b.z, a.x*b.y - a.y*b.x};
}
__device__ __forceinline__ float f3dot(F3 a, F3 b) { return a.x*b.x + a.y*b.y + a.z*b.z; }

__device__ __forceinline__ void dihedral_from(F3 A, F3 B, F3 mid,
                                              float& s, float& c) {
    float x = f3dot(A, B);
    F3 w = f3cross(A, B);
    float y = f3dot(w, mid) * rsqrtf(fmaxf(f3dot(mid, mid), 1e-30f));
    float r2 = x * x + y * y;
    float rinv = rsqrtf(r2);
    bool ok = r2 > 1e-24f;
    s = ok ? y * rinv : 0.0f;   // atan2(0,0)=0 -> angle 0
    c = ok ? x * rinv : 1.0f;
}

// fr_g = dr_g @ Ra(angle): rotation-about-x folded column-wise; trans = dt.
struct Xf12 { float m[9]; float t[3]; };
__device__ __forceinline__ Xf12 mk_fr(float4 r0, float4 r1, float4 r2,
                                      float sA, float cA) {
    Xf12 o;
    o.m[0] = r0.x; o.m[1] = fmaf(cA, r0.y, sA * r0.z); o.m[2] = fmaf(cA, r0.z, -sA * r0.y);
    o.m[3] = r1.x; o.m[4] = fmaf(cA, r1.y, sA * r1.z); o.m[5] = fmaf(cA, r1.z, -sA * r1.y);
    o.m[6] = r2.x; o.m[7] = fmaf(cA, r2.y, sA * r2.z); o.m[8] = fmaf(cA, r2.z, -sA * r2.y);
    o.t[0] = r0.w; o.t[1] = r1.w; o.t[2] = r2.w;
    return o;
}

__device__ __forceinline__ void cond_apply(const Xf12& F, bool cond,
                                           float& qx, float& qy, float& qz) {
    float tx = fmaf(F.m[0], qx, fmaf(F.m[1], qy, fmaf(F.m[2], qz, F.t[0])));
    float ty = fmaf(F.m[3], qx, fmaf(F.m[4], qy, fmaf(F.m[5], qz, F.t[1])));
    float tz = fmaf(F.m[6], qx, fmaf(F.m[7], qy, fmaf(F.m[8], qz, F.t[2])));
    qx = cond ? tx : qx; qy = cond ? ty : qy; qz = cond ? tz : qz;
}

__device__ __forceinline__ float2 h2f(float packed) {
    __half2 h = *reinterpret_cast<__half2*>(&packed);
    return __half22float2(h);
}

#define OT_STRIDE 34    // dwords/row: v[0..29] + sc overlap at [18..33];
                        // 34 = 2 mod 32 -> 2-lane bank pairing on b64 ops
#define AUV_AA    62    // dwords/aa in AUV table: 10 atoms x 6 + 2 pad;
                        // 62 = 30 mod 32 -> 16 bank positions, b64-aligned

__global__ __launch_bounds__(256)
__attribute__((amdgpu_waves_per_eu(2, 4)))
void idealizer_kernel(
    const int*   __restrict__ aa,       // (n,)
    const float* __restrict__ bb,       // (n,4,3)
    const float* __restrict__ tor,      // (n,4)
    const float* __restrict__ dframes,  // (21,8,4,4)
    const int*   __restrict__ gidx,     // (21,14)
    const float* __restrict__ amask,    // (21,14)
    const float* __restrict__ lit,      // (21,14,3)
    float*       __restrict__ out,      // (n,14,3)
    int n)
{
    __shared__ __align__(16) float s_ot[256 * OT_STRIDE];  // 34816 B
    __shared__ __align__(16) float s_auv[21 * AUV_AA];     //  5208 B
    __shared__ unsigned s_gpk[21];   // 10 x 3-bit group ids (atoms 4..13)
    __shared__ unsigned s_mbit[21];  // 10 x 1-bit atom mask (atoms 4..13)
    // total 40192 B -> 4 blocks/CU

    const int tid = threadIdx.x;

    // ---- stage per-(aa,atom) constants A (fp32), U,V (fp16) ----
    // q_local = A + c*U + s*V  with A = dr[:,0]*lx + dt,
    // U = dr[:,1]*ly + dr[:,2]*lz, V = dr[:,2]*ly - dr[:,1]*lz.
    if (tid < 210) {
        int aai = (tid * 6554) >> 16;        // tid/10, exact for tid<210
        int a   = tid - aai * 10;
        int g   = gidx[aai * 14 + 4 + a];
        const float4* dr4 = (const float4*)dframes + (aai * 8 + g) * 4;
        float4 d0 = dr4[0], d1 = dr4[1], d2 = dr4[2];
        const float* lp = lit + aai * 42 + 12 + a * 3;
        float lx = lp[0], ly = lp[1], lz = lp[2];
        float* w = &s_auv[aai * AUV_AA + a * 6];
        w[0] = fmaf(d0.x, lx, d0.w);
        w[1] = fmaf(d1.x, lx, d1.w);
        w[2] = fmaf(d2.x, lx, d2.w);
        float U0 = fmaf(d0.y, ly, d0.z * lz), V0 = fmaf(d0.z, ly, -d0.y * lz);
        float U1 = fmaf(d1.y, ly, d1.z * lz), V1 = fmaf(d1.z, ly, -d1.y * lz);
        float U2 = fmaf(d2.y, ly, d2.z * lz), V2 = fmaf(d2.z, ly, -d2.y * lz);
        ((__half2*)w)[3] = __floats2half2_rn(U0, U1);
        ((__half2*)w)[4] = __floats2half2_rn(U2, V0);
        ((__half2*)w)[5] = __floats2half2_rn(V1, V2);
    }
    if (tid < 21) {
        unsigned gp = 0, mb = 0;
        #pragma unroll
        for (int a = 0; a < 10; a++) {
            gp |= ((unsigned)gidx[tid * 14 + 4 + a]) << (3 * a);
            mb |= (amask[tid * 14 + 4 + a] != 0.0f ? 1u : 0u) << a;
        }
        s_gpk[tid] = gp;
        s_mbit[tid] = mb;
    }
    __syncthreads();

    const int i0 = blockIdx.x * 256;
    const int i  = i0 + tid;
    if (i < n) {
        // ---- issue ALL global loads first ----
        const int aai = aa[i];
        const float4* bb4 = (const float4*)bb;
        float4 q0 = bb4[i * 3 + 0];   // N.xyz, CA.x
        float4 q1 = bb4[i * 3 + 1];   // CA.yz, C.xy
        float Cz  = bb[i * 12 + 8];
        const int im = (i > 0)     ? i - 1 : 0;
        const int ip = (i < n - 1) ? i + 1 : 0;
        float4 t1 = bb4[im * 3 + 1];                 // C[i-1].xy in .z,.w
        float  t2 = bb[im * 12 + 8];                 // C[i-1].z
        float4 r0 = bb4[ip * 3 + 0];                 // N[i+1], CA[i+1].x
        float2 r1 = ((const float2*)bb)[ip * 6 + 2]; // CA[i+1].yz
        float4 tv = ((const float4*)tor)[i];
        // chained-group frames dr4,dr5,dr6 (tiny table, L1-hot)
        const float4* dfp = (const float4*)dframes + (aai * 32 + 16);
        float4 e40 = dfp[0], e41 = dfp[1],  e42 = dfp[2];
        float4 e50 = dfp[4], e51 = dfp[5],  e52 = dfp[6];
        float4 e60 = dfp[8], e61 = dfp[9],  e62 = dfp[10];

        const unsigned gpk  = s_gpk[aai];
        const unsigned mbit = s_mbit[aai];

        F3 Np  = {q0.x, q0.y, q0.z};
        F3 CAp = {q0.w, q1.x, q1.y};
        F3 Cp  = {q1.z, q1.w, Cz};
        F3 Cm  = {t1.z, t1.w, t2};
        F3 Nn  = {r0.x, r0.y, r0.z};
        F3 CAn = {r0.w, r1.x, r1.y};

        // ---- backbone dihedrals via shared bond crosses ----
        F3 u1 = f3sub(Np, Cm);
        F3 u2 = f3sub(CAp, Np);
        F3 u3 = f3sub(Cp, CAp);
        F3 u4 = f3sub(Nn, Cp);
        F3 u5 = f3sub(CAn, Nn);
        F3 c12 = f3cross(u1, u2), c23 = f3cross(u2, u3);
        F3 c34 = f3cross(u3, u4), c45 = f3cross(u4, u5);
        float s_ph, c_ph, s_ps, c_ps, s_om, c_om;
        dihedral_from(c12, c23, u2, s_ph, c_ph);   // phi
        dihedral_from(c23, c34, u3, s_ps, c_ps);   // psi
        dihedral_from(c34, c45, u4, s_om, c_om);   // omega
        if (i == 0)     { s_ph = 0.0f; c_ph = 1.0f; }
        if (i == n - 1) { s_ps = 0.0f; c_ps = 1.0f; s_om = 0.0f; c_om = 1.0f; }

        // ---- backbone frame from reference (N, CA, C) ----
        const float eps = 1e-20f;
        F3 nv = f3sub(Np, CAp);
        F3 cv = f3sub(Cp, CAp);
        float cx = cv.x, cy = cv.y, cz2 = cv.z;
        float d2xy  = cx * cx + cy * cy;
        float inrm  = rsqrtf(eps + d2xy);
        float s1 = -cy * inrm, c1 = cx * inrm;
        float inrm2 = rsqrtf(eps + d2xy + cz2 * cz2);
        float s2v = cz2 * inrm2, c2v = sqrtf(d2xy) * inrm2;
        float Rc00 = c2v * c1,  Rc01 = -c2v * s1, Rc02 = s2v;
        float Rc10 = s1,        Rc11 = c1,        Rc12 = 0.0f;
        float Rc20 = -s2v * c1, Rc21 = s2v * s1,  Rc22 = c2v;
        float n2y = Rc10 * nv.x + Rc11 * nv.y + Rc12 * nv.z;
        float n2z = Rc20 * nv.x + Rc21 * nv.y + Rc22 * nv.z;
        float inrm3 = rsqrtf(eps + n2y * n2y + n2z * n2z);
        float sn = -n2z * inrm3, cn = n2y * inrm3;
        float M10 = cn * Rc10 - sn * Rc20, M11 = cn * Rc11 - sn * Rc21, M12 = cn * Rc12 - sn * Rc22;
        float M20 = sn * Rc10 + cn * Rc20, M21 = sn * Rc11 + cn * Rc21;
        float M22 = sn * Rc12 + cn * Rc22;
        // bb_r = (Rn @ Rc)^T
        float B00 = Rc00, B01 = M10, B02 = M20;
        float B10 = Rc01, B11 = M11, B12 = M21;
        float B20 = Rc02, B21 = M12, B22 = M22;

        // ---- per-frame sin/cos: [identity, omega, phi, psi, tor0..3] ----
        float sang[8], cang[8];
        sang[0] = 0.0f; cang[0] = 1.0f;
        sang[1] = s_om; cang[1] = c_om;
        sang[2] = s_ph; cang[2] = c_ph;
        sang[3] = s_ps; cang[3] = c_ps;
        __sincosf(tv.x, &sang[4], &cang[4]);
        __sincosf(tv.y, &sang[5], &cang[5]);
        __sincosf(tv.z, &sang[6], &cang[6]);
        __sincosf(tv.w, &sang[7], &cang[7]);

        // sc -> per-thread LDS row slots [18..33] (fp32 pairs, read by
        // runtime g in the atom loop; overlapped region is written by v
        // only AFTER all atom reads complete)
        float* row = &s_ot[tid * OT_STRIDE];
        float2* scw = (float2*)(row + 18);
        #pragma unroll
        for (int g8 = 0; g8 < 8; g8++)
            scw[g8] = make_float2(sang[g8], cang[g8]);

        // chained-group frames (uniform across the atom loop)
        const Xf12 F4 = mk_fr(e40, e41, e42, sang[4], cang[4]);
        const Xf12 F5 = mk_fr(e50, e51, e52, sang[5], cang[5]);
        const Xf12 F6 = mk_fr(e60, e61, e62, sang[6], cang[6]);

        float v[30];
        const float* auv = &s_auv[aai * AUV_AA];
        #pragma unroll
        for (int a = 0; a < 10; a++) {
            int g = (gpk >> (3 * a)) & 7;
            // sin/cos for this atom's group (runtime g -> LDS, not regs)
            float2 sc = *(const float2*)(row + 18 + 2 * g);
            // per-(aa,atom) constants
            const float* ap = auv + a * 6;
            float2 w0 = *(const float2*)ap;        // A0, A1
            float2 w1 = *(const float2*)(ap + 2);  // A2, pk(U0,U1)
            float2 w2 = *(const float2*)(ap + 4);  // pk(U2,V0), pk(V1,V2)
            float2 u01  = h2f(w1.y);
            float2 u2v0 = h2f(w2.x);
            float2 v12  = h2f(w2.y);
            // q_local = A + c*U + s*V   (= dr_g @ (Ra@lit) + dt_g)
            float qx = fmaf(sc.y, u01.x,  fmaf(sc.x, u2v0.y, w0.x));
            float qy = fmaf(sc.y, u01.y,  fmaf(sc.x, v12.x,  w0.y));
            float qz = fmaf(sc.y, u2v0.x, fmaf(sc.x, v12.y,  w1.x));
            // chain: apply fr6 if g>=7, fr5 if g>=6, fr4 if g>=5
            cond_apply(F6, g >= 7, qx, qy, qz);
            cond_apply(F5, g >= 6, qx, qy, qz);
            cond_apply(F4, g >= 5, qx, qy, qz);
            // backbone frame + mask
            float mk = ((mbit >> a) & 1u) ? 1.0f : 0.0f;
            v[3*a]   = mk * fmaf(B00, qx, fmaf(B01, qy, fmaf(B02, qz, CAp.x)));
            v[3*a+1] = mk * fmaf(B10, qx, fmaf(B11, qy, fmaf(B12, qz, CAp.y)));
            v[3*a+2] = mk * fmaf(B20, qx, fmaf(B21, qy, fmaf(B22, qz, CAp.z)));
        }

        // ---- tile row write: 15 x ds_write_b64 ----
        float2* so2 = (float2*)row;
        #pragma unroll
        for (int k = 0; k < 15; k++)
            so2[k] = make_float2(v[2*k], v[2*k+1]);
    }

    __syncthreads();

    // ---- coalesced copy-out, division-free ----
    int m = n - i0; if (m > 256) m = 256;
    float2* gout = (float2*)(out + (size_t)i0 * 42);
    const float2* bbt = (const float2*)(bb + (size_t)i0 * 12);
    if (m == 256) {
        int r = (tid * 24967) >> 19;   // tid/21 (magic, exact for 0..255)
        int j = tid - r * 21;
        #pragma unroll
        for (int k = 0; k < 21; k++) {
            int off = tid + (k << 8);
            int bi = (j < 6) ? (r * 6 + j) : 0;        // clamped-safe index
            float2 gval = bbt[bi];
            int tj = (j < 6) ? 0 : (j - 6);
            const float* tp = &s_ot[r * OT_STRIDE + 2 * tj];
            float2 lval = make_float2(tp[0], tp[1]);
            gout[off] = (j < 6) ? gval : lval;
            r += 12; j += 4;                           // 256 = 12*21 + 4
            if (j >= 21) { j -= 21; r += 1; }
        }
    } else {
        const int cnt2 = m * 21;
        int r = tid / 21;
        int j = tid - r * 21;
        for (int off = tid; off < cnt2; off += 256) {
            int bi = (j < 6) ? (r * 6 + j) : 0;
            float2 gval = bbt[bi];
            int tj = (j < 6) ? 0 : (j - 6);
            const float* tp = &s_ot[r * OT_STRIDE + 2 * tj];
            float2 lval = make_float2(tp[0], tp[1]);
            gout[off] = (j < 6) ? gval : lval;
            r += 12; j += 4;
            if (j >= 21) { j -= 21; r += 1; }
        }
    }
}

extern "C" void kernel_launch(void* const* d_in, const int* in_sizes, int n_in,
                              void* d_out, int out_size, void* d_ws, size_t ws_size,
                              hipStream_t stream) {
    const int*   aa  = (const int*)d_in[0];
    const float* bb  = (const float*)d_in[1];
    const float* tor = (const float*)d_in[2];
    const float* df  = (const float*)d_in[3];
    const int*   gi  = (const int*)d_in[4];
    const float* am  = (const float*)d_in[5];
    const float* lp  = (const float*)d_in[6];
    float* outp = (float*)d_out;
    const int n = in_sizes[0];
    const int blocks = (n + 255) / 256;   // one 256-residue tile per block
    idealizer_kernel<<<blocks, 256, 0, stream>>>(aa, bb, tor, df, gi, am, lp, outp, n);
}